// Round 10
// baseline (3544.785 us; speedup 1.0000x reference)
//
#include <hip/hip_runtime.h>
#include <cstddef>
#include <cstdint>

#define T_STEPS 80
#define BATCH   256
#define DIM     4936
#define EMB     200
#define DE      5136
#define HID     512
#define SIXH    3072
#define FIVEH   2560
#define NCLS    151
#define NPACK   15504
#define NKT     156          // ceil(4936/32) for px; Kpad = 4992
#define NKT_H   16           // 512/32 for ps
#define NCOMB   2816         // 2560 (Wst) + 256 (Wout padded)

typedef unsigned short ushort_t;
typedef short short8 __attribute__((ext_vector_type(8)));
typedef float f32x4 __attribute__((ext_vector_type(4)));

__device__ inline ushort_t f2bf_rn(float x) {
    union { float f; uint32_t u; } v; v.f = x;
    uint32_t u = v.u;
    return (ushort_t)((u + 0x7FFFu + ((u >> 16) & 1u)) >> 16);
}
__device__ inline float bf2f(ushort_t b) {
    union { float f; uint32_t u; } v; v.u = ((uint32_t)b) << 16;
    return v.f;
}
__device__ inline float sigmoidf(float x) { return 1.f / (1.f + expf(-x)); }

// ---------------------------------------------------------------------------
// convert_split: src [ntiles*128 rows, ld] fp32 -> hi/lo bf16 in tiled layout
// out[mtile][ktile][kb(4)][row(128)][8]   (zero-padded for k >= kvalid)
// ---------------------------------------------------------------------------
__global__ __launch_bounds__(256) void convert_split(
    const float* __restrict__ src, int ld, int kvalid,
    ushort_t* __restrict__ hi, ushort_t* __restrict__ lo, int nktiles)
{
    __shared__ float s[128][33];
    const int tid = threadIdx.x;
    const int kt  = blockIdx.x;
    const int mt  = blockIdx.y;

#pragma unroll
    for (int it = 0; it < 4; ++it) {
        int idx = it * 256 + tid;          // 1024 float4 slots
        int row = idx >> 3;
        int f4  = idx & 7;
        int k   = kt * 32 + f4 * 4;
        const float* p = src + (size_t)(mt * 128 + row) * ld + k;
        float4 v;
        if (k + 3 < kvalid) v = *(const float4*)p;
        else {
            v.x = (k + 0) < kvalid ? p[0] : 0.f;
            v.y = (k + 1) < kvalid ? p[1] : 0.f;
            v.z = (k + 2) < kvalid ? p[2] : 0.f;
            v.w = (k + 3) < kvalid ? p[3] : 0.f;
        }
        s[row][f4 * 4 + 0] = v.x; s[row][f4 * 4 + 1] = v.y;
        s[row][f4 * 4 + 2] = v.z; s[row][f4 * 4 + 3] = v.w;
    }
    __syncthreads();

    const size_t base = ((size_t)mt * nktiles + kt) * 4096;
#pragma unroll
    for (int it = 0; it < 2; ++it) {
        int o   = it * 256 + tid;          // 512 chunks of 8 ushorts
        int kb  = o >> 7;
        int row = o & 127;
        alignas(16) ushort_t hbuf[8];
        alignas(16) ushort_t lbuf[8];
#pragma unroll
        for (int e = 0; e < 8; ++e) {
            float x = s[row][kb * 8 + e];
            ushort_t hh = f2bf_rn(x);
            float lof = x - bf2f(hh);
            hbuf[e] = hh;
            lbuf[e] = f2bf_rn(lof);
        }
        *(uint4*)(hi + base + (size_t)o * 8) = *(const uint4*)hbuf;
        *(uint4*)(lo + base + (size_t)o * 8) = *(const uint4*)lbuf;
    }
}

// ---------------------------------------------------------------------------
__device__ inline void gload16(const ushort_t* g, ushort_t* l) {
    __builtin_amdgcn_global_load_lds(
        (const __attribute__((address_space(1))) void*)g,
        (__attribute__((address_space(3))) void*)l, 16, 0, 0);
}

// ---------------------------------------------------------------------------
// mfma3: OUT[m,n] = bias[n] + sum_k A[m,k]*B[n,k] via 3-term split bf16.
// 256x128 tile, BK=32, 8 waves (512 thr). NO LDS: fragments stream
// global -> registers directly (pre-tiled layout makes each lane's fragment
// a coalesced 16B dwordx4). 2-deep register pipeline, no barriers, waves
// free-run; duplicate cross-wave reads are served by L1/L2.
// ---------------------------------------------------------------------------
__global__ __launch_bounds__(512, 2) void mfma3(
    const ushort_t* __restrict__ Ah, const ushort_t* __restrict__ Al,
    const ushort_t* __restrict__ Bh, const ushort_t* __restrict__ Bl,
    const float* __restrict__ bias, float* __restrict__ OUT,
    int nkt, int ldout)
{
    const int tid  = threadIdx.x;
    const int wave = tid >> 6;
    const int lane = tid & 63;
    const int ntb = blockIdx.x, mtb = blockIdx.y;
    const int wr = wave >> 1, wc = wave & 1;   // wr 0..3 (64-row slabs), wc 0..1

    f32x4 acc[4][4];
#pragma unroll
    for (int i = 0; i < 4; ++i)
#pragma unroll
        for (int j = 0; j < 4; ++j) acc[i][j] = (f32x4){0.f, 0.f, 0.f, 0.f};

    const int kb = lane >> 4;
    const int lr = lane & 15;
    // A tiles: m-tile index 2*mtb + (wr>>1); within tile rows (wr&1)*64 + lr
    const size_t abase = ((size_t)(2 * mtb + (wr >> 1))) * nkt * 4096;
    const size_t bbase = (size_t)ntb * nkt * 4096;
    const int aoff = kb * 1024 + ((wr & 1) * 64 + lr) * 8;
    const int boff = kb * 1024 + (wc * 64 + lr) * 8;

    const ushort_t* pa_h = Ah + abase + aoff;
    const ushort_t* pa_l = Al + abase + aoff;
    const ushort_t* pb_h = Bh + bbase + boff;
    const ushort_t* pb_l = Bl + bbase + boff;

#define LOADSET(ah_, al_, bh_, bl_, kt_) do {                          \
        const size_t o_ = (size_t)(kt_) * 4096;                        \
        _Pragma("unroll")                                              \
        for (int i_ = 0; i_ < 4; ++i_) {                               \
            ah_[i_] = *(const short8*)(pa_h + o_ + i_ * 128);          \
            al_[i_] = *(const short8*)(pa_l + o_ + i_ * 128);          \
        }                                                              \
        _Pragma("unroll")                                              \
        for (int j_ = 0; j_ < 4; ++j_) {                               \
            bh_[j_] = *(const short8*)(pb_h + o_ + j_ * 128);          \
            bl_[j_] = *(const short8*)(pb_l + o_ + j_ * 128);          \
        }                                                              \
    } while (0)

#define MFMASET(ah_, al_, bh_, bl_) do {                               \
        _Pragma("unroll")                                              \
        for (int i_ = 0; i_ < 4; ++i_)                                 \
            _Pragma("unroll")                                          \
            for (int j_ = 0; j_ < 4; ++j_) {                           \
                acc[i_][j_] = __builtin_amdgcn_mfma_f32_16x16x32_bf16(ah_[i_], bh_[j_], acc[i_][j_], 0, 0, 0); \
                acc[i_][j_] = __builtin_amdgcn_mfma_f32_16x16x32_bf16(ah_[i_], bl_[j_], acc[i_][j_], 0, 0, 0); \
                acc[i_][j_] = __builtin_amdgcn_mfma_f32_16x16x32_bf16(al_[i_], bh_[j_], acc[i_][j_], 0, 0, 0); \
            }                                                          \
    } while (0)

    short8 ah0[4], al0[4], bh0[4], bl0[4];
    short8 ah1[4], al1[4], bh1[4], bl1[4];

    LOADSET(ah0, al0, bh0, bl0, 0);
    for (int kt = 0; kt < nkt; kt += 2) {
        if (kt + 1 < nkt) LOADSET(ah1, al1, bh1, bl1, kt + 1);
        MFMASET(ah0, al0, bh0, bl0);
        if (kt + 2 < nkt) LOADSET(ah0, al0, bh0, bl0, kt + 2);
        if (kt + 1 < nkt) MFMASET(ah1, al1, bh1, bl1);
    }
#undef LOADSET
#undef MFMASET

#pragma unroll
    for (int i = 0; i < 4; ++i) {
        const int row = mtb * 256 + wr * 64 + i * 16 + (lane >> 4) * 4;
#pragma unroll
        for (int j = 0; j < 4; ++j) {
            const int col = ntb * 128 + wc * 64 + j * 16 + (lane & 15);
            const float bv = bias[col];
#pragma unroll
            for (int r = 0; r < 4; ++r)
                OUT[(size_t)(row + r) * ldout + col] = acc[i][j][r] + bv;
        }
    }
}

// ---------------------------------------------------------------------------
// ps_splitk: partial[ks][m,n] = sum_{k in slice ks} h[m,k]*Wcomb[n,k]
// Wcomb = [Wst (2560 rows); Wout padded (256 rows)] -> N = 2816, 44 ntiles.
// 64x64 tile, K-split 4. All 4 K-iters staged at once (64 KB LDS), ONE
// barrier, then 48 straight MFMAs. 704 blocks -> TLP.
// ---------------------------------------------------------------------------
__global__ __launch_bounds__(256) void ps_splitk(
    const ushort_t* __restrict__ hH, const ushort_t* __restrict__ hL,
    const ushort_t* __restrict__ WcH, const ushort_t* __restrict__ WcL,
    float* __restrict__ partial)   // [4][256][2816]
{
    __shared__ ushort_t sAh[8192], sAl[8192], sBh[8192], sBl[8192]; // 64 KiB

    const int tid  = threadIdx.x;
    const int wave = tid >> 6;
    const int lane = tid & 63;
    const int ntile = blockIdx.x;   // 0..43
    const int mtile = blockIdx.y;   // 0..3
    const int ks    = blockIdx.z;   // 0..3
    const int amt = mtile >> 1, arh = mtile & 1;
    const int bmt = ntile >> 1, brh = ntile & 1;
    const int wr = wave >> 1, wc = wave & 1;

    f32x4 acc[2][2];
#pragma unroll
    for (int i = 0; i < 2; ++i)
#pragma unroll
        for (int j = 0; j < 2; ++j) acc[i][j] = (f32x4){0.f, 0.f, 0.f, 0.f};

    const int lw    = wave * 512;
    const int lsrcA = wave * 1024 + arh * 512 + lane * 8;
    const int lsrcB = wave * 1024 + brh * 512 + lane * 8;

#pragma unroll
    for (int ki = 0; ki < 4; ++ki) {
        const int kt = ks * 4 + ki;
        const size_t atile = ((size_t)(amt * NKT_H + kt)) * 4096;
        const size_t btile = ((size_t)(bmt * NKT_H + kt)) * 4096;
        gload16(hH  + atile + lsrcA, &sAh[ki * 2048 + lw]);
        gload16(hL  + atile + lsrcA, &sAl[ki * 2048 + lw]);
        gload16(WcH + btile + lsrcB, &sBh[ki * 2048 + lw]);
        gload16(WcL + btile + lsrcB, &sBl[ki * 2048 + lw]);
    }
    __syncthreads();   // single drain: all 16 stages visible

    const int kb = lane >> 4;
    const int lr = lane & 15;
#pragma unroll
    for (int ki = 0; ki < 4; ++ki) {
        short8 ah[2], al[2], bh[2], bl[2];
#pragma unroll
        for (int i = 0; i < 2; ++i) {
            const int ao = ki * 2048 + kb * 512 + (wr * 32 + i * 16 + lr) * 8;
            ah[i] = *(const short8*)&sAh[ao];
            al[i] = *(const short8*)&sAl[ao];
        }
#pragma unroll
        for (int j = 0; j < 2; ++j) {
            const int bo = ki * 2048 + kb * 512 + (wc * 32 + j * 16 + lr) * 8;
            bh[j] = *(const short8*)&sBh[bo];
            bl[j] = *(const short8*)&sBl[bo];
        }
#pragma unroll
        for (int i = 0; i < 2; ++i)
#pragma unroll
            for (int j = 0; j < 2; ++j) {
                acc[i][j] = __builtin_amdgcn_mfma_f32_16x16x32_bf16(ah[i], bh[j], acc[i][j], 0, 0, 0);
                acc[i][j] = __builtin_amdgcn_mfma_f32_16x16x32_bf16(ah[i], bl[j], acc[i][j], 0, 0, 0);
                acc[i][j] = __builtin_amdgcn_mfma_f32_16x16x32_bf16(al[i], bh[j], acc[i][j], 0, 0, 0);
            }
    }

    float* out = partial + ((size_t)ks * 256 + mtile * 64) * NCOMB + ntile * 64;
#pragma unroll
    for (int i = 0; i < 2; ++i) {
        const int row = wr * 32 + i * 16 + (lane >> 4) * 4;
#pragma unroll
        for (int j = 0; j < 2; ++j) {
            const int col = wc * 32 + j * 16 + (lane & 15);
#pragma unroll
            for (int r = 0; r < 4; ++r)
                out[(size_t)(row + r) * NCOMB + col] = acc[i][j][r];
        }
    }
}

// ---------------------------------------------------------------------------
// ew_gemm: EW[m,n] = sum_k embed[m,k] * Win[n, 4936+k]   (m<152, K=200)
// ---------------------------------------------------------------------------
__global__ __launch_bounds__(256) void ew_gemm(
    const float* __restrict__ embed, const float* __restrict__ Win,
    float* __restrict__ EW)
{
    __shared__ float As[16][68];
    __shared__ float Bs[16][68];
    const int tid = threadIdx.x;
    const int tx  = tid & 15;
    const int ty  = tid >> 4;
    const int n0  = blockIdx.x * 64;
    const int m0  = blockIdx.y * 64;
    const int lrow = tid >> 2;
    const int lk   = (tid & 3) * 4;

    float acc[4][4];
#pragma unroll
    for (int i = 0; i < 4; ++i)
#pragma unroll
        for (int j = 0; j < 4; ++j) acc[i][j] = 0.f;

    for (int k0 = 0; k0 < EMB; k0 += 16) {
        int k = k0 + lk;
        float4 av = {0.f,0.f,0.f,0.f}, bv = {0.f,0.f,0.f,0.f};
        if (k < EMB) {
            int am = m0 + lrow;
            if (am < 152) av = *(const float4*)(embed + (size_t)am * EMB + k);
            bv = *(const float4*)(Win + (size_t)(n0 + lrow) * DE + DIM + k);
        }
        __syncthreads();
        As[lk + 0][lrow] = av.x; As[lk + 1][lrow] = av.y;
        As[lk + 2][lrow] = av.z; As[lk + 3][lrow] = av.w;
        Bs[lk + 0][lrow] = bv.x; Bs[lk + 1][lrow] = bv.y;
        Bs[lk + 2][lrow] = bv.z; Bs[lk + 3][lrow] = bv.w;
        __syncthreads();
#pragma unroll
        for (int kk = 0; kk < 16; ++kk) {
            float4 a4 = *(const float4*)&As[kk][ty * 4];
            float4 b4 = *(const float4*)&Bs[kk][tx * 4];
            float avr[4] = {a4.x, a4.y, a4.z, a4.w};
            float bvr[4] = {b4.x, b4.y, b4.z, b4.w};
#pragma unroll
            for (int i = 0; i < 4; ++i)
#pragma unroll
                for (int j = 0; j < 4; ++j)
                    acc[i][j] = fmaf(avr[i], bvr[j], acc[i][j]);
        }
    }
#pragma unroll
    for (int i = 0; i < 4; ++i) {
        int m = m0 + ty * 4 + i;
        if (m < 152) {
#pragma unroll
            for (int j = 0; j < 4; ++j)
                EW[(size_t)m * SIXH + n0 + tx * 4 + j] = acc[i][j];
        }
    }
}

// ---------------------------------------------------------------------------
// pad_wout: padW[256][512] = Wout rows 0..150, zero rows 151..255
// ---------------------------------------------------------------------------
__global__ __launch_bounds__(256) void pad_wout(
    const float* __restrict__ Wout, float* __restrict__ padW)
{
    int i = blockIdx.x * 256 + threadIdx.x;
    if (i < 256 * 512) {
        int row = i >> 9;
        padW[i] = (row < NCLS) ? Wout[i] : 0.f;
    }
}

// init: c = 0, tiled h hi/lo = 0 (first ps partials == 0). In-graph -> det.
__global__ __launch_bounds__(256) void init_state(
    float* __restrict__ c, ushort_t* __restrict__ hHt, ushort_t* __restrict__ hLt)
{
    int i = blockIdx.x * 256 + threadIdx.x;
    if (i < BATCH * HID) { c[i] = 0.f; hHt[i] = 0; hLt[i] = 0; }
}

// ---------------------------------------------------------------------------
// step_fused(t): 256 blocks x 1 batch row.
//  1) preds[t-1] = b_out + sum_ks partial[ks][b][2560+cls]  (pred-deferral);
//     argmax -> commit[t-1] -> erow.
//  2) gates from px_t + EW[erow] + sum_ks partial cols 0..2559 + b_state;
//     c,h update; h emits (tiled bf16 for next ps, fp32 for finalize).
// ---------------------------------------------------------------------------
__global__ __launch_bounds__(256) void step_fused(
    const float* __restrict__ px_t,        // [256, 3072]
    const float* __restrict__ EW,          // [152, 3072]
    const float* __restrict__ partial,     // [4][256][2816]
    const float* __restrict__ b_state,     // [2560]
    const float* __restrict__ b_out,       // [151]
    int first,
    ushort_t* __restrict__ hHt, ushort_t* __restrict__ hLt,
    float* __restrict__ c, float* __restrict__ hF,
    float* __restrict__ dists_prev,        // dists[t-1] (unused if first)
    int*   __restrict__ commit_prev)       // commits[t-1] (write; unused if first)
{
    __shared__ float hs[HID];
    __shared__ float preds_s[NCLS + 1];
    __shared__ int   commit_sh;

    const int tid = threadIdx.x;
    const int b   = blockIdx.x;

    int erow = 0;
    if (!first) {
        if (tid < NCLS) {
            const float* pq = partial + (size_t)b * NCOMB + 2560;
            float pr = b_out[tid] + pq[tid]
                     + pq[(size_t)256 * NCOMB + tid]
                     + pq[(size_t)2 * 256 * NCOMB + tid]
                     + pq[(size_t)3 * 256 * NCOMB + tid];
            preds_s[tid] = pr;
            dists_prev[(size_t)b * NCLS + tid] = pr;
        }
        __syncthreads();
        if (tid == 0) {
            int bi = 1; float bv = preds_s[1];
            for (int n = 2; n < NCLS; ++n) {
                float v = preds_s[n];
                if (v > bv) { bv = v; bi = n; }
            }
            commit_prev[b] = bi;
            commit_sh = bi;
        }
        __syncthreads();
        erow = commit_sh + 1;
    }

    const float* ew = EW + (size_t)erow * SIXH;
    const float* px = px_t + (size_t)b * SIXH;
    const float* pp = partial + (size_t)b * NCOMB;

#pragma unroll
    for (int it = 0; it < 2; ++it) {
        const int u = it * 256 + tid;
        float p[6];
#pragma unroll
        for (int k2 = 0; k2 < 5; ++k2) {
            const int o = k2 * HID + u;
            float s = pp[o] + pp[(size_t)256 * NCOMB + o]
                    + pp[(size_t)2 * 256 * NCOMB + o] + pp[(size_t)3 * 256 * NCOMB + o];
            p[k2] = px[o] + ew[o] + s + b_state[o];
        }
        p[5] = px[5 * HID + u] + ew[5 * HID + u];

        float i_g = sigmoidf(p[0]);
        float f_g = sigmoidf(p[1]);
        float m_i = tanhf(p[2]);
        float o_g = sigmoidf(p[3]);
        float c_new = i_g * m_i + f_g * c[(size_t)b * HID + u];
        float outv  = o_g * tanhf(c_new);
        float hw    = sigmoidf(p[4]);
        float h_new = hw * outv + (1.f - hw) * p[5];
        c[(size_t)b * HID + u]  = c_new;
        hF[(size_t)b * HID + u] = h_new;
        hs[u] = h_new;
    }
    __syncthreads();

    // tiled bf16 h emit for next step's ps GEMM
    if (tid < 128) {
        const int half = tid >> 6;
        const int ch   = tid & 63;
        const int mt   = b >> 7;
        const int row  = b & 127;
        const size_t off = ((size_t)(mt * NKT_H + (ch >> 2))) * 4096
                         + (size_t)(ch & 3) * 1024 + (size_t)row * 8;
        alignas(16) ushort_t buf[8];
        if (half == 0) {
#pragma unroll
            for (int e = 0; e < 8; ++e) buf[e] = f2bf_rn(hs[ch * 8 + e]);
            *(uint4*)(hHt + off) = *(const uint4*)buf;
        } else {
#pragma unroll
            for (int e = 0; e < 8; ++e) {
                float x = hs[ch * 8 + e];
                buf[e] = f2bf_rn(x - bf2f(f2bf_rn(x)));
            }
            *(uint4*)(hLt + off) = *(const uint4*)buf;
        }
    }
}

// ---------------------------------------------------------------------------
// finalize_last: preds for t = T-1 from fp32 h, argmax, dists+commits write.
// ---------------------------------------------------------------------------
__global__ __launch_bounds__(192) void finalize_last(
    const float* __restrict__ hF, const float* __restrict__ Wout,
    const float* __restrict__ b_out,
    float* __restrict__ dists_last, int* __restrict__ commits_last)
{
    __shared__ float hsh[HID];
    __shared__ float preds[NCLS + 1];
    const int b = blockIdx.x;
    const int tid = threadIdx.x;

    if (tid < 128) {
        float4 v = *(const float4*)(hF + (size_t)b * HID + tid * 4);
        *(float4*)&hsh[tid * 4] = v;
    }
    __syncthreads();
    if (tid < NCLS) {
        const float* w = Wout + (size_t)tid * HID;
        float s0 = 0.f, s1 = 0.f, s2 = 0.f, s3 = 0.f;
        for (int k = 0; k < HID; k += 4) {
            float4 w4 = *(const float4*)(w + k);
            float4 h4 = *(const float4*)&hsh[k];
            s0 = fmaf(h4.x, w4.x, s0);
            s1 = fmaf(h4.y, w4.y, s1);
            s2 = fmaf(h4.z, w4.z, s2);
            s3 = fmaf(h4.w, w4.w, s3);
        }
        float s = b_out[tid] + ((s0 + s1) + (s2 + s3));
        preds[tid] = s;
        dists_last[(size_t)b * NCLS + tid] = s;
    }
    __syncthreads();
    if (tid == 0) {
        int bi = 1; float bv = preds[1];
        for (int n = 2; n < NCLS; ++n) {
            float v = preds[n];
            if (v > bv) { bv = v; bi = n; }
        }
        commits_last[b] = bi;
    }
}

// ---------------------------------------------------------------------------
__global__ __launch_bounds__(192) void gather_out(
    const float* __restrict__ dists, const int* __restrict__ commits,
    const int* __restrict__ gidx, float* __restrict__ out)
{
    const int i = blockIdx.x;
    const int g = gidx[i];
    if (threadIdx.x < NCLS)
        out[(size_t)i * NCLS + threadIdx.x] = dists[(size_t)g * NCLS + threadIdx.x];
    if (threadIdx.x == NCLS)
        out[(size_t)NPACK * NCLS + i] = (float)commits[g];
}

// ---------------------------------------------------------------------------
extern "C" void kernel_launch(void* const* d_in, const int* in_sizes, int n_in,
                              void* d_out, int out_size, void* d_ws, size_t ws_size,
                              hipStream_t stream)
{
    const float* X      = (const float*)d_in[0];  // [80,256,4936]
    const float* embed  = (const float*)d_in[1];  // [152,200]
    const float* Win    = (const float*)d_in[2];  // [3072,5136]
    const float* b_in   = (const float*)d_in[3];
    const float* Wst    = (const float*)d_in[4];  // [2560,512]
    const float* b_st   = (const float*)d_in[5];
    const float* Wout   = (const float*)d_in[6];  // [151,512]
    const float* b_out  = (const float*)d_in[7];
    const int*   gidx   = (const int*)d_in[8];

    const size_t WN  = (size_t)24 * NKT * 4096;     // ushorts per Win-split array
    const size_t WCN = (size_t)22 * NKT_H * 4096;   // ushorts per Wcomb-split array
    const size_t HN  = (size_t)2 * NKT_H * 4096;    // ushorts per h-split array

    ushort_t* Wh  = (ushort_t*)d_ws;
    ushort_t* Wl  = Wh + WN;
    ushort_t* WcH = Wl + WN;
    ushort_t* WcL = WcH + WCN;
    ushort_t* hHt = WcL + WCN;
    ushort_t* hLt = hHt + HN;
    float* EW      = (float*)(hLt + HN);
    float* partial = EW + (size_t)152 * SIXH;             // 4*256*2816
    float* c       = partial + (size_t)4 * BATCH * NCOMB;
    float* hF      = c + (size_t)BATCH * HID;
    float* padW    = hF + (size_t)BATCH * HID;            // 256*512
    float* dists   = padW + (size_t)256 * HID;
    int* commits   = (int*)(dists + (size_t)T_STEPS * BATCH * NCLS);
    char* cbase    = (char*)(commits + T_STEPS * BATCH);

    size_t off = (size_t)(cbase - (char*)d_ws);
    off = (off + 255) & ~(size_t)255;
    const size_t per_t = (size_t)2 * 2 * NKT * 4096 * 2 + (size_t)BATCH * SIXH * 4;
    size_t rem = (ws_size > off) ? (ws_size - off) : 0;
    int CT = (int)(rem / per_t);
    if (CT > T_STEPS) CT = T_STEPS;
    if (CT < 1) CT = 1;

    ushort_t* Xh = (ushort_t*)((char*)d_ws + off);
    ushort_t* Xl = Xh + (size_t)2 * CT * NKT * 4096;
    float* px    = (float*)(Xl + (size_t)2 * CT * NKT * 4096);

    // one-time prep
    convert_split<<<dim3(NKT, 24), 256, 0, stream>>>(Win, DE, DIM, Wh, Wl, NKT);
    convert_split<<<dim3(NKT_H, 20), 256, 0, stream>>>(Wst, HID, HID, WcH, WcL, NKT_H);
    pad_wout<<<512, 256, 0, stream>>>(Wout, padW);
    convert_split<<<dim3(NKT_H, 2), 256, 0, stream>>>(
        padW, HID, HID, WcH + (size_t)20 * NKT_H * 4096, WcL + (size_t)20 * NKT_H * 4096, NKT_H);
    ew_gemm<<<dim3(SIXH / 64, 3), 256, 0, stream>>>(embed, Win, EW);
    init_state<<<512, 256, 0, stream>>>(c, hHt, hLt);

    for (int t0 = 0; t0 < T_STEPS; t0 += CT) {
        int nt = T_STEPS - t0;
        if (nt > CT) nt = CT;
        convert_split<<<dim3(NKT, 2 * nt), 256, 0, stream>>>(
            X + (size_t)t0 * BATCH * DIM, DIM, DIM, Xh, Xl, NKT);
        mfma3<<<dim3(SIXH / 128, nt), 512, 0, stream>>>(
            Xh, Xl, Wh, Wl, b_in, px, NKT, SIXH);
        for (int t = t0; t < t0 + nt; ++t) {
            const int tp = (t > 0) ? t - 1 : 0;
            ps_splitk<<<dim3(44, 4, 4), 256, 0, stream>>>(
                hHt, hLt, WcH, WcL, partial);
            step_fused<<<BATCH, 256, 0, stream>>>(
                px + (size_t)(t - t0) * BATCH * SIXH, EW, partial, b_st, b_out,
                (t == 0) ? 1 : 0, hHt, hLt, c, hF,
                dists + (size_t)tp * BATCH * NCLS, commits + (size_t)tp * BATCH);
        }
    }

    finalize_last<<<BATCH, 192, 0, stream>>>(
        hF, Wout, b_out,
        dists + (size_t)(T_STEPS - 1) * BATCH * NCLS,
        commits + (size_t)(T_STEPS - 1) * BATCH);

    gather_out<<<NPACK, 192, 0, stream>>>(dists, commits, gidx, (float*)d_out);
}

// Round 11
// 3238.041 us; speedup vs baseline: 1.0947x; 1.0947x over previous
//
#include <hip/hip_runtime.h>
#include <cstddef>
#include <cstdint>

#define T_STEPS 80
#define BATCH   256
#define DIM     4936
#define EMB     200
#define DE      5136
#define HID     512
#define SIXH    3072
#define FIVEH   2560
#define NCLS    151
#define NPACK   15504
#define NKT     156          // ceil(4936/32) for px; Kpad = 4992
#define NKT_H   16           // 512/32 for ps
#define NCOMB   2816         // 2560 (Wst) + 256 (Wout padded)
#define BUFSZ   24576        // ushorts per pipeline buffer (48 KiB)

typedef unsigned short ushort_t;
typedef short short8 __attribute__((ext_vector_type(8)));
typedef float f32x4 __attribute__((ext_vector_type(4)));

__device__ inline ushort_t f2bf_rn(float x) {
    union { float f; uint32_t u; } v; v.f = x;
    uint32_t u = v.u;
    return (ushort_t)((u + 0x7FFFu + ((u >> 16) & 1u)) >> 16);
}
__device__ inline float bf2f(ushort_t b) {
    union { float f; uint32_t u; } v; v.u = ((uint32_t)b) << 16;
    return v.f;
}
__device__ inline float sigmoidf(float x) { return 1.f / (1.f + expf(-x)); }

// ---------------------------------------------------------------------------
// convert_split: src [ntiles*128 rows, ld] fp32 -> hi/lo bf16 in tiled layout
// out[mtile][ktile][kb(4)][row(128)][8]   (zero-padded for k >= kvalid)
// ---------------------------------------------------------------------------
__global__ __launch_bounds__(256) void convert_split(
    const float* __restrict__ src, int ld, int kvalid,
    ushort_t* __restrict__ hi, ushort_t* __restrict__ lo, int nktiles)
{
    __shared__ float s[128][33];
    const int tid = threadIdx.x;
    const int kt  = blockIdx.x;
    const int mt  = blockIdx.y;

#pragma unroll
    for (int it = 0; it < 4; ++it) {
        int idx = it * 256 + tid;          // 1024 float4 slots
        int row = idx >> 3;
        int f4  = idx & 7;
        int k   = kt * 32 + f4 * 4;
        const float* p = src + (size_t)(mt * 128 + row) * ld + k;
        float4 v;
        if (k + 3 < kvalid) v = *(const float4*)p;
        else {
            v.x = (k + 0) < kvalid ? p[0] : 0.f;
            v.y = (k + 1) < kvalid ? p[1] : 0.f;
            v.z = (k + 2) < kvalid ? p[2] : 0.f;
            v.w = (k + 3) < kvalid ? p[3] : 0.f;
        }
        s[row][f4 * 4 + 0] = v.x; s[row][f4 * 4 + 1] = v.y;
        s[row][f4 * 4 + 2] = v.z; s[row][f4 * 4 + 3] = v.w;
    }
    __syncthreads();

    const size_t base = ((size_t)mt * nktiles + kt) * 4096;
#pragma unroll
    for (int it = 0; it < 2; ++it) {
        int o   = it * 256 + tid;          // 512 chunks of 8 ushorts
        int kb  = o >> 7;
        int row = o & 127;
        alignas(16) ushort_t hbuf[8];
        alignas(16) ushort_t lbuf[8];
#pragma unroll
        for (int e = 0; e < 8; ++e) {
            float x = s[row][kb * 8 + e];
            ushort_t hh = f2bf_rn(x);
            float lof = x - bf2f(hh);
            hbuf[e] = hh;
            lbuf[e] = f2bf_rn(lof);
        }
        *(uint4*)(hi + base + (size_t)o * 8) = *(const uint4*)hbuf;
        *(uint4*)(lo + base + (size_t)o * 8) = *(const uint4*)lbuf;
    }
}

// ---------------------------------------------------------------------------
__device__ inline void gload16(const ushort_t* g, ushort_t* l) {
    __builtin_amdgcn_global_load_lds(
        (const __attribute__((address_space(1))) void*)g,
        (__attribute__((address_space(3))) void*)l, 16, 0, 0);
}

// ---------------------------------------------------------------------------
// mfma3: OUT[m,n] = bias[n] + sum_k A[m,k]*B[n,k] via 3-term split bf16.
// 256x128 tile, BK=32, 8 waves (512 thr). 3-stage depth-2 pipeline with
// counted vmcnt(6) (never 0 in steady state) + one barrier per iter.
// T5: s_setprio(1) around the MFMA cluster (phase-split schedule -> waves
// have role diversity; scheduler favors MFMA-issuing waves).
// Dynamic LDS: 3 x 48 KiB. Per buf: Ah[2x4096] Al[2x4096] Bh[4096] Bl[4096].
// ---------------------------------------------------------------------------
__global__ __launch_bounds__(512, 1) void mfma3(
    const ushort_t* __restrict__ Ah, const ushort_t* __restrict__ Al,
    const ushort_t* __restrict__ Bh, const ushort_t* __restrict__ Bl,
    const float* __restrict__ bias, float* __restrict__ OUT,
    int nkt, int ldout)
{
    extern __shared__ __align__(16) ushort_t smem[];   // 3 * BUFSZ ushorts

    const int tid  = threadIdx.x;
    const int wave = tid >> 6;
    const int lane = tid & 63;
    const int ntb = blockIdx.x, mtb = blockIdx.y;
    const int wr = wave >> 1, wc = wave & 1;   // wr 0..3 (rows), wc 0..1 (cols)

    f32x4 acc[4][4];
#pragma unroll
    for (int i = 0; i < 4; ++i)
#pragma unroll
        for (int j = 0; j < 4; ++j) acc[i][j] = (f32x4){0.f, 0.f, 0.f, 0.f};

    const size_t a0 = (size_t)(2 * mtb) * nkt * 4096;
    const size_t a1 = a0 + (size_t)nkt * 4096;
    const size_t bb = (size_t)ntb * nkt * 4096;

    const int kb = lane >> 4;
    const int lr = lane & 15;
    // A local: [mtile(2)][kb(4)][row(128)][8]; wave rows = wr*64..+63
    const int aoffl = (wr >> 1) * 4096 + kb * 1024 + ((wr & 1) * 64 + lr) * 8;
    // B local: [kb(4)][row(128)][8]; wave cols = wc*64..+63
    const int boffl = kb * 1024 + (wc * 64 + lr) * 8;

#define STAGE3(slot, kt_) do {                                      \
        ushort_t* d = smem + (slot) * BUFSZ;                        \
        const size_t ko = (size_t)(kt_) * 4096 + tid * 8;           \
        gload16(Ah + a0 + ko, d + tid * 8);                         \
        gload16(Ah + a1 + ko, d + 4096 + tid * 8);                  \
        gload16(Al + a0 + ko, d + 8192 + tid * 8);                  \
        gload16(Al + a1 + ko, d + 12288 + tid * 8);                 \
        gload16(Bh + bb + ko, d + 16384 + tid * 8);                 \
        gload16(Bl + bb + ko, d + 20480 + tid * 8);                 \
    } while (0)

    // prologue: two stages in flight (12 outstanding loads/thread)
    STAGE3(0, 0);
    if (nkt > 1) STAGE3(1, 1);

    int cb = 0;
    for (int kt = 0; kt < nkt; ++kt) {
        // complete S(kt): steady state leaves S(kt+1)'s 6 loads in flight
        if (kt < nkt - 1) asm volatile("s_waitcnt vmcnt(6)" ::: "memory");
        else              asm volatile("s_waitcnt vmcnt(0)" ::: "memory");
        __builtin_amdgcn_sched_barrier(0);
        __builtin_amdgcn_s_barrier();      // all waves: loads done, prev reads done
        if (kt + 2 < nkt) {
            int s2 = cb + 2; if (s2 >= 3) s2 -= 3;
            STAGE3(s2, kt + 2);            // overwrites slot of compute(kt-1): safe
        }

        const ushort_t* p  = smem + cb * BUFSZ;
        const ushort_t* pB = p + 16384;
        short8 ah[4], al[4], bh[4], bl[4];
#pragma unroll
        for (int i = 0; i < 4; ++i) {
            ah[i] = *(const short8*)&p[aoffl + i * 128];
            al[i] = *(const short8*)&p[8192 + aoffl + i * 128];
        }
#pragma unroll
        for (int j = 0; j < 4; ++j) {
            bh[j] = *(const short8*)&pB[boffl + j * 128];
            bl[j] = *(const short8*)&pB[4096 + boffl + j * 128];
        }
        __builtin_amdgcn_s_setprio(1);
#pragma unroll
        for (int i = 0; i < 4; ++i)
#pragma unroll
            for (int j = 0; j < 4; ++j) {
                acc[i][j] = __builtin_amdgcn_mfma_f32_16x16x32_bf16(ah[i], bh[j], acc[i][j], 0, 0, 0);
                acc[i][j] = __builtin_amdgcn_mfma_f32_16x16x32_bf16(ah[i], bl[j], acc[i][j], 0, 0, 0);
                acc[i][j] = __builtin_amdgcn_mfma_f32_16x16x32_bf16(al[i], bh[j], acc[i][j], 0, 0, 0);
            }
        __builtin_amdgcn_s_setprio(0);

        cb = (cb == 2) ? 0 : cb + 1;
    }
#undef STAGE3

#pragma unroll
    for (int i = 0; i < 4; ++i) {
        const int row = mtb * 256 + wr * 64 + i * 16 + (lane >> 4) * 4;
#pragma unroll
        for (int j = 0; j < 4; ++j) {
            const int col = ntb * 128 + wc * 64 + j * 16 + (lane & 15);
            const float bv = bias[col];
#pragma unroll
            for (int r = 0; r < 4; ++r)
                OUT[(size_t)(row + r) * ldout + col] = acc[i][j][r] + bv;
        }
    }
}

// ---------------------------------------------------------------------------
// ps_splitk: partial[ks][m,n] = sum_{k in slice ks} h[m,k]*Wcomb[n,k]
// Wcomb = [Wst (2560 rows); Wout padded (256 rows)] -> N = 2816, 44 ntiles.
// 64x64 tile, K-split 4. All 4 K-iters staged at once (64 KB LDS), ONE
// barrier, then 48 straight MFMAs. 704 blocks -> TLP.
// ---------------------------------------------------------------------------
__global__ __launch_bounds__(256) void ps_splitk(
    const ushort_t* __restrict__ hH, const ushort_t* __restrict__ hL,
    const ushort_t* __restrict__ WcH, const ushort_t* __restrict__ WcL,
    float* __restrict__ partial)   // [4][256][2816]
{
    __shared__ ushort_t sAh[8192], sAl[8192], sBh[8192], sBl[8192]; // 64 KiB

    const int tid  = threadIdx.x;
    const int wave = tid >> 6;
    const int lane = tid & 63;
    const int ntile = blockIdx.x;   // 0..43
    const int mtile = blockIdx.y;   // 0..3
    const int ks    = blockIdx.z;   // 0..3
    const int amt = mtile >> 1, arh = mtile & 1;
    const int bmt = ntile >> 1, brh = ntile & 1;
    const int wr = wave >> 1, wc = wave & 1;

    f32x4 acc[2][2];
#pragma unroll
    for (int i = 0; i < 2; ++i)
#pragma unroll
        for (int j = 0; j < 2; ++j) acc[i][j] = (f32x4){0.f, 0.f, 0.f, 0.f};

    const int lw    = wave * 512;
    const int lsrcA = wave * 1024 + arh * 512 + lane * 8;
    const int lsrcB = wave * 1024 + brh * 512 + lane * 8;

#pragma unroll
    for (int ki = 0; ki < 4; ++ki) {
        const int kt = ks * 4 + ki;
        const size_t atile = ((size_t)(amt * NKT_H + kt)) * 4096;
        const size_t btile = ((size_t)(bmt * NKT_H + kt)) * 4096;
        gload16(hH  + atile + lsrcA, &sAh[ki * 2048 + lw]);
        gload16(hL  + atile + lsrcA, &sAl[ki * 2048 + lw]);
        gload16(WcH + btile + lsrcB, &sBh[ki * 2048 + lw]);
        gload16(WcL + btile + lsrcB, &sBl[ki * 2048 + lw]);
    }
    __syncthreads();   // single drain: all 16 stages visible

    const int kb = lane >> 4;
    const int lr = lane & 15;
#pragma unroll
    for (int ki = 0; ki < 4; ++ki) {
        short8 ah[2], al[2], bh[2], bl[2];
#pragma unroll
        for (int i = 0; i < 2; ++i) {
            const int ao = ki * 2048 + kb * 512 + (wr * 32 + i * 16 + lr) * 8;
            ah[i] = *(const short8*)&sAh[ao];
            al[i] = *(const short8*)&sAl[ao];
        }
#pragma unroll
        for (int j = 0; j < 2; ++j) {
            const int bo = ki * 2048 + kb * 512 + (wc * 32 + j * 16 + lr) * 8;
            bh[j] = *(const short8*)&sBh[bo];
            bl[j] = *(const short8*)&sBl[bo];
        }
#pragma unroll
        for (int i = 0; i < 2; ++i)
#pragma unroll
            for (int j = 0; j < 2; ++j) {
                acc[i][j] = __builtin_amdgcn_mfma_f32_16x16x32_bf16(ah[i], bh[j], acc[i][j], 0, 0, 0);
                acc[i][j] = __builtin_amdgcn_mfma_f32_16x16x32_bf16(ah[i], bl[j], acc[i][j], 0, 0, 0);
                acc[i][j] = __builtin_amdgcn_mfma_f32_16x16x32_bf16(al[i], bh[j], acc[i][j], 0, 0, 0);
            }
    }

    float* out = partial + ((size_t)ks * 256 + mtile * 64) * NCOMB + ntile * 64;
#pragma unroll
    for (int i = 0; i < 2; ++i) {
        const int row = wr * 32 + i * 16 + (lane >> 4) * 4;
#pragma unroll
        for (int j = 0; j < 2; ++j) {
            const int col = wc * 32 + j * 16 + (lane & 15);
#pragma unroll
            for (int r = 0; r < 4; ++r)
                out[(size_t)(row + r) * NCOMB + col] = acc[i][j][r];
        }
    }
}

// ---------------------------------------------------------------------------
// ew_gemm: EW[m,n] = sum_k embed[m,k] * Win[n, 4936+k]   (m<152, K=200)
// ---------------------------------------------------------------------------
__global__ __launch_bounds__(256) void ew_gemm(
    const float* __restrict__ embed, const float* __restrict__ Win,
    float* __restrict__ EW)
{
    __shared__ float As[16][68];
    __shared__ float Bs[16][68];
    const int tid = threadIdx.x;
    const int tx  = tid & 15;
    const int ty  = tid >> 4;
    const int n0  = blockIdx.x * 64;
    const int m0  = blockIdx.y * 64;
    const int lrow = tid >> 2;
    const int lk   = (tid & 3) * 4;

    float acc[4][4];
#pragma unroll
    for (int i = 0; i < 4; ++i)
#pragma unroll
        for (int j = 0; j < 4; ++j) acc[i][j] = 0.f;

    for (int k0 = 0; k0 < EMB; k0 += 16) {
        int k = k0 + lk;
        float4 av = {0.f,0.f,0.f,0.f}, bv = {0.f,0.f,0.f,0.f};
        if (k < EMB) {
            int am = m0 + lrow;
            if (am < 152) av = *(const float4*)(embed + (size_t)am * EMB + k);
            bv = *(const float4*)(Win + (size_t)(n0 + lrow) * DE + DIM + k);
        }
        __syncthreads();
        As[lk + 0][lrow] = av.x; As[lk + 1][lrow] = av.y;
        As[lk + 2][lrow] = av.z; As[lk + 3][lrow] = av.w;
        Bs[lk + 0][lrow] = bv.x; Bs[lk + 1][lrow] = bv.y;
        Bs[lk + 2][lrow] = bv.z; Bs[lk + 3][lrow] = bv.w;
        __syncthreads();
#pragma unroll
        for (int kk = 0; kk < 16; ++kk) {
            float4 a4 = *(const float4*)&As[kk][ty * 4];
            float4 b4 = *(const float4*)&Bs[kk][tx * 4];
            float avr[4] = {a4.x, a4.y, a4.z, a4.w};
            float bvr[4] = {b4.x, b4.y, b4.z, b4.w};
#pragma unroll
            for (int i = 0; i < 4; ++i)
#pragma unroll
                for (int j = 0; j < 4; ++j)
                    acc[i][j] = fmaf(avr[i], bvr[j], acc[i][j]);
        }
    }
#pragma unroll
    for (int i = 0; i < 4; ++i) {
        int m = m0 + ty * 4 + i;
        if (m < 152) {
#pragma unroll
            for (int j = 0; j < 4; ++j)
                EW[(size_t)m * SIXH + n0 + tx * 4 + j] = acc[i][j];
        }
    }
}

// ---------------------------------------------------------------------------
// pad_wout: padW[256][512] = Wout rows 0..150, zero rows 151..255
// ---------------------------------------------------------------------------
__global__ __launch_bounds__(256) void pad_wout(
    const float* __restrict__ Wout, float* __restrict__ padW)
{
    int i = blockIdx.x * 256 + threadIdx.x;
    if (i < 256 * 512) {
        int row = i >> 9;
        padW[i] = (row < NCLS) ? Wout[i] : 0.f;
    }
}

// init: c = 0, tiled h hi/lo = 0 (first ps partials == 0). In-graph -> det.
__global__ __launch_bounds__(256) void init_state(
    float* __restrict__ c, ushort_t* __restrict__ hHt, ushort_t* __restrict__ hLt)
{
    int i = blockIdx.x * 256 + threadIdx.x;
    if (i < BATCH * HID) { c[i] = 0.f; hHt[i] = 0; hLt[i] = 0; }
}

// ---------------------------------------------------------------------------
// step_fused(t): 256 blocks x 1 batch row.
//  1) preds[t-1] = b_out + sum_ks partial[ks][b][2560+cls]  (pred-deferral);
//     argmax -> commit[t-1] -> erow.
//  2) gates from px_t + EW[erow] + sum_ks partial cols 0..2559 + b_state;
//     c,h update; h emits (tiled bf16 for next ps, fp32 for finalize).
// ---------------------------------------------------------------------------
__global__ __launch_bounds__(256) void step_fused(
    const float* __restrict__ px_t,        // [256, 3072]
    const float* __restrict__ EW,          // [152, 3072]
    const float* __restrict__ partial,     // [4][256][2816]
    const float* __restrict__ b_state,     // [2560]
    const float* __restrict__ b_out,       // [151]
    int first,
    ushort_t* __restrict__ hHt, ushort_t* __restrict__ hLt,
    float* __restrict__ c, float* __restrict__ hF,
    float* __restrict__ dists_prev,        // dists[t-1] (unused if first)
    int*   __restrict__ commit_prev)       // commits[t-1] (write; unused if first)
{
    __shared__ float hs[HID];
    __shared__ float preds_s[NCLS + 1];
    __shared__ int   commit_sh;

    const int tid = threadIdx.x;
    const int b   = blockIdx.x;

    int erow = 0;
    if (!first) {
        if (tid < NCLS) {
            const float* pq = partial + (size_t)b * NCOMB + 2560;
            float pr = b_out[tid] + pq[tid]
                     + pq[(size_t)256 * NCOMB + tid]
                     + pq[(size_t)2 * 256 * NCOMB + tid]
                     + pq[(size_t)3 * 256 * NCOMB + tid];
            preds_s[tid] = pr;
            dists_prev[(size_t)b * NCLS + tid] = pr;
        }
        __syncthreads();
        if (tid == 0) {
            int bi = 1; float bv = preds_s[1];
            for (int n = 2; n < NCLS; ++n) {
                float v = preds_s[n];
                if (v > bv) { bv = v; bi = n; }
            }
            commit_prev[b] = bi;
            commit_sh = bi;
        }
        __syncthreads();
        erow = commit_sh + 1;
    }

    const float* ew = EW + (size_t)erow * SIXH;
    const float* px = px_t + (size_t)b * SIXH;
    const float* pp = partial + (size_t)b * NCOMB;

#pragma unroll
    for (int it = 0; it < 2; ++it) {
        const int u = it * 256 + tid;
        float p[6];
#pragma unroll
        for (int k2 = 0; k2 < 5; ++k2) {
            const int o = k2 * HID + u;
            float s = pp[o] + pp[(size_t)256 * NCOMB + o]
                    + pp[(size_t)2 * 256 * NCOMB + o] + pp[(size_t)3 * 256 * NCOMB + o];
            p[k2] = px[o] + ew[o] + s + b_state[o];
        }
        p[5] = px[5 * HID + u] + ew[5 * HID + u];

        float i_g = sigmoidf(p[0]);
        float f_g = sigmoidf(p[1]);
        float m_i = tanhf(p[2]);
        float o_g = sigmoidf(p[3]);
        float c_new = i_g * m_i + f_g * c[(size_t)b * HID + u];
        float outv  = o_g * tanhf(c_new);
        float hw    = sigmoidf(p[4]);
        float h_new = hw * outv + (1.f - hw) * p[5];
        c[(size_t)b * HID + u]  = c_new;
        hF[(size_t)b * HID + u] = h_new;
        hs[u] = h_new;
    }
    __syncthreads();

    // tiled bf16 h emit for next step's ps GEMM
    if (tid < 128) {
        const int half = tid >> 6;
        const int ch   = tid & 63;
        const int mt   = b >> 7;
        const int row  = b & 127;
        const size_t off = ((size_t)(mt * NKT_H + (ch >> 2))) * 4096
                         + (size_t)(ch & 3) * 1024 + (size_t)row * 8;
        alignas(16) ushort_t buf[8];
        if (half == 0) {
#pragma unroll
            for (int e = 0; e < 8; ++e) buf[e] = f2bf_rn(hs[ch * 8 + e]);
            *(uint4*)(hHt + off) = *(const uint4*)buf;
        } else {
#pragma unroll
            for (int e = 0; e < 8; ++e) {
                float x = hs[ch * 8 + e];
                buf[e] = f2bf_rn(x - bf2f(f2bf_rn(x)));
            }
            *(uint4*)(hLt + off) = *(const uint4*)buf;
        }
    }
}

// ---------------------------------------------------------------------------
// finalize_last: preds for t = T-1 from fp32 h, argmax, dists+commits write.
// ---------------------------------------------------------------------------
__global__ __launch_bounds__(192) void finalize_last(
    const float* __restrict__ hF, const float* __restrict__ Wout,
    const float* __restrict__ b_out,
    float* __restrict__ dists_last, int* __restrict__ commits_last)
{
    __shared__ float hsh[HID];
    __shared__ float preds[NCLS + 1];
    const int b = blockIdx.x;
    const int tid = threadIdx.x;

    if (tid < 128) {
        float4 v = *(const float4*)(hF + (size_t)b * HID + tid * 4);
        *(float4*)&hsh[tid * 4] = v;
    }
    __syncthreads();
    if (tid < NCLS) {
        const float* w = Wout + (size_t)tid * HID;
        float s0 = 0.f, s1 = 0.f, s2 = 0.f, s3 = 0.f;
        for (int k = 0; k < HID; k += 4) {
            float4 w4 = *(const float4*)(w + k);
            float4 h4 = *(const float4*)&hsh[k];
            s0 = fmaf(h4.x, w4.x, s0);
            s1 = fmaf(h4.y, w4.y, s1);
            s2 = fmaf(h4.z, w4.z, s2);
            s3 = fmaf(h4.w, w4.w, s3);
        }
        float s = b_out[tid] + ((s0 + s1) + (s2 + s3));
        preds[tid] = s;
        dists_last[(size_t)b * NCLS + tid] = s;
    }
    __syncthreads();
    if (tid == 0) {
        int bi = 1; float bv = preds[1];
        for (int n = 2; n < NCLS; ++n) {
            float v = preds[n];
            if (v > bv) { bv = v; bi = n; }
        }
        commits_last[b] = bi;
    }
}

// ---------------------------------------------------------------------------
__global__ __launch_bounds__(192) void gather_out(
    const float* __restrict__ dists, const int* __restrict__ commits,
    const int* __restrict__ gidx, float* __restrict__ out)
{
    const int i = blockIdx.x;
    const int g = gidx[i];
    if (threadIdx.x < NCLS)
        out[(size_t)i * NCLS + threadIdx.x] = dists[(size_t)g * NCLS + threadIdx.x];
    if (threadIdx.x == NCLS)
        out[(size_t)NPACK * NCLS + i] = (float)commits[g];
}

// ---------------------------------------------------------------------------
extern "C" void kernel_launch(void* const* d_in, const int* in_sizes, int n_in,
                              void* d_out, int out_size, void* d_ws, size_t ws_size,
                              hipStream_t stream)
{
    const float* X      = (const float*)d_in[0];  // [80,256,4936]
    const float* embed  = (const float*)d_in[1];  // [152,200]
    const float* Win    = (const float*)d_in[2];  // [3072,5136]
    const float* b_in   = (const float*)d_in[3];
    const float* Wst    = (const float*)d_in[4];  // [2560,512]
    const float* b_st   = (const float*)d_in[5];
    const float* Wout   = (const float*)d_in[6];  // [151,512]
    const float* b_out  = (const float*)d_in[7];
    const int*   gidx   = (const int*)d_in[8];

    // raise dynamic-LDS cap for mfma3 (idempotent; capture-safe host call)
    hipFuncSetAttribute((const void*)mfma3,
                        hipFuncAttributeMaxDynamicSharedMemorySize,
                        3 * BUFSZ * 2);

    const size_t WN  = (size_t)24 * NKT * 4096;     // ushorts per Win-split array
    const size_t WCN = (size_t)22 * NKT_H * 4096;   // ushorts per Wcomb-split array
    const size_t HN  = (size_t)2 * NKT_H * 4096;    // ushorts per h-split array

    ushort_t* Wh  = (ushort_t*)d_ws;
    ushort_t* Wl  = Wh + WN;
    ushort_t* WcH = Wl + WN;
    ushort_t* WcL = WcH + WCN;
    ushort_t* hHt = WcL + WCN;
    ushort_t* hLt = hHt + HN;
    float* EW      = (float*)(hLt + HN);
    float* partial = EW + (size_t)152 * SIXH;             // 4*256*2816
    float* c       = partial + (size_t)4 * BATCH * NCOMB;
    float* hF      = c + (size_t)BATCH * HID;
    float* padW    = hF + (size_t)BATCH * HID;            // 256*512
    float* dists   = padW + (size_t)256 * HID;
    int* commits   = (int*)(dists + (size_t)T_STEPS * BATCH * NCLS);
    char* cbase    = (char*)(commits + T_STEPS * BATCH);

    size_t off = (size_t)(cbase - (char*)d_ws);
    off = (off + 255) & ~(size_t)255;
    const size_t per_t = (size_t)2 * 2 * NKT * 4096 * 2 + (size_t)BATCH * SIXH * 4;
    size_t rem = (ws_size > off) ? (ws_size - off) : 0;
    int CT = (int)(rem / per_t);
    if (CT > T_STEPS) CT = T_STEPS;
    if (CT < 1) CT = 1;

    ushort_t* Xh = (ushort_t*)((char*)d_ws + off);
    ushort_t* Xl = Xh + (size_t)2 * CT * NKT * 4096;
    float* px    = (float*)(Xl + (size_t)2 * CT * NKT * 4096);

    // one-time prep
    convert_split<<<dim3(NKT, 24), 256, 0, stream>>>(Win, DE, DIM, Wh, Wl, NKT);
    convert_split<<<dim3(NKT_H, 20), 256, 0, stream>>>(Wst, HID, HID, WcH, WcL, NKT_H);
    pad_wout<<<512, 256, 0, stream>>>(Wout, padW);
    convert_split<<<dim3(NKT_H, 2), 256, 0, stream>>>(
        padW, HID, HID, WcH + (size_t)20 * NKT_H * 4096, WcL + (size_t)20 * NKT_H * 4096, NKT_H);
    ew_gemm<<<dim3(SIXH / 64, 3), 256, 0, stream>>>(embed, Win, EW);
    init_state<<<512, 256, 0, stream>>>(c, hHt, hLt);

    for (int t0 = 0; t0 < T_STEPS; t0 += CT) {
        int nt = T_STEPS - t0;
        if (nt > CT) nt = CT;
        convert_split<<<dim3(NKT, 2 * nt), 256, 0, stream>>>(
            X + (size_t)t0 * BATCH * DIM, DIM, DIM, Xh, Xl, NKT);
        mfma3<<<dim3(SIXH / 128, nt), 512, 3 * BUFSZ * 2, stream>>>(
            Xh, Xl, Wh, Wl, b_in, px, NKT, SIXH);
        for (int t = t0; t < t0 + nt; ++t) {
            const int tp = (t > 0) ? t - 1 : 0;
            ps_splitk<<<dim3(44, 4, 4), 256, 0, stream>>>(
                hHt, hLt, WcH, WcL, partial);
            step_fused<<<BATCH, 256, 0, stream>>>(
                px + (size_t)(t - t0) * BATCH * SIXH, EW, partial, b_st, b_out,
                (t == 0) ? 1 : 0, hHt, hLt, c, hF,
                dists + (size_t)tp * BATCH * NCLS, commits + (size_t)tp * BATCH);
        }
    }

    finalize_last<<<BATCH, 192, 0, stream>>>(
        hF, Wout, b_out,
        dists + (size_t)(T_STEPS - 1) * BATCH * NCLS,
        commits + (size_t)(T_STEPS - 1) * BATCH);

    gather_out<<<NPACK, 192, 0, stream>>>(dists, commits, gidx, (float*)d_out);
}

// Round 12
// 3210.686 us; speedup vs baseline: 1.1041x; 1.0085x over previous
//
#include <hip/hip_runtime.h>
#include <cstddef>
#include <cstdint>

#define T_STEPS 80
#define BATCH   256
#define DIM     4936
#define EMB     200
#define DE      5136
#define HID     512
#define SIXH    3072
#define FIVEH   2560
#define NCLS    151
#define NPACK   15504
#define NKT     156          // ceil(4936/32) for px; Kpad = 4992
#define NKT_H   16           // 512/32 for ps
#define NCOMB   2816         // 2560 (Wst) + 256 (Wout padded)
#define BUF2SZ  32768        // ushorts per pipeline stage (64 KiB)

typedef unsigned short ushort_t;
typedef short short8 __attribute__((ext_vector_type(8)));
typedef float f32x4 __attribute__((ext_vector_type(4)));
typedef float f32x16 __attribute__((ext_vector_type(16)));

__device__ inline ushort_t f2bf_rn(float x) {
    union { float f; uint32_t u; } v; v.f = x;
    uint32_t u = v.u;
    return (ushort_t)((u + 0x7FFFu + ((u >> 16) & 1u)) >> 16);
}
__device__ inline float bf2f(ushort_t b) {
    union { float f; uint32_t u; } v; v.u = ((uint32_t)b) << 16;
    return v.f;
}
__device__ inline float sigmoidf(float x) { return 1.f / (1.f + expf(-x)); }

// ---------------------------------------------------------------------------
// convert_split: src [ntiles*128 rows, ld] fp32 -> hi/lo bf16 in tiled layout
// out[mtile][ktile][kb(4)][row(128)][8]   (zero-padded for k >= kvalid)
// ---------------------------------------------------------------------------
__global__ __launch_bounds__(256) void convert_split(
    const float* __restrict__ src, int ld, int kvalid,
    ushort_t* __restrict__ hi, ushort_t* __restrict__ lo, int nktiles)
{
    __shared__ float s[128][33];
    const int tid = threadIdx.x;
    const int kt  = blockIdx.x;
    const int mt  = blockIdx.y;

#pragma unroll
    for (int it = 0; it < 4; ++it) {
        int idx = it * 256 + tid;          // 1024 float4 slots
        int row = idx >> 3;
        int f4  = idx & 7;
        int k   = kt * 32 + f4 * 4;
        const float* p = src + (size_t)(mt * 128 + row) * ld + k;
        float4 v;
        if (k + 3 < kvalid) v = *(const float4*)p;
        else {
            v.x = (k + 0) < kvalid ? p[0] : 0.f;
            v.y = (k + 1) < kvalid ? p[1] : 0.f;
            v.z = (k + 2) < kvalid ? p[2] : 0.f;
            v.w = (k + 3) < kvalid ? p[3] : 0.f;
        }
        s[row][f4 * 4 + 0] = v.x; s[row][f4 * 4 + 1] = v.y;
        s[row][f4 * 4 + 2] = v.z; s[row][f4 * 4 + 3] = v.w;
    }
    __syncthreads();

    const size_t base = ((size_t)mt * nktiles + kt) * 4096;
#pragma unroll
    for (int it = 0; it < 2; ++it) {
        int o   = it * 256 + tid;          // 512 chunks of 8 ushorts
        int kb  = o >> 7;
        int row = o & 127;
        alignas(16) ushort_t hbuf[8];
        alignas(16) ushort_t lbuf[8];
#pragma unroll
        for (int e = 0; e < 8; ++e) {
            float x = s[row][kb * 8 + e];
            ushort_t hh = f2bf_rn(x);
            float lof = x - bf2f(hh);
            hbuf[e] = hh;
            lbuf[e] = f2bf_rn(lof);
        }
        *(uint4*)(hi + base + (size_t)o * 8) = *(const uint4*)hbuf;
        *(uint4*)(lo + base + (size_t)o * 8) = *(const uint4*)lbuf;
    }
}

// ---------------------------------------------------------------------------
__device__ inline void gload16(const ushort_t* g, ushort_t* l) {
    __builtin_amdgcn_global_load_lds(
        (const __attribute__((address_space(1))) void*)g,
        (__attribute__((address_space(3))) void*)l, 16, 0, 0);
}

// ---------------------------------------------------------------------------
// mfma3: OUT[m,n] = bias[n] + sum_k A[m,k]*B[n,k] via 3-term split bf16.
// 256x256 tile, BK=32, 8 waves (2 row-slabs x 4 col-slabs), wave tile
// 128x64, mfma_f32_32x32x16_bf16 (C/D: col=lane&31,
// row=(reg&3)+8*(reg>>2)+4*(lane>>5); operand: lane holds row l&31,
// k-group l>>5). Double-buffered LDS (2 x 64 KiB), 1 barrier/iter,
// stage(kt+1) issued right after the barrier (one compute of slack).
// ---------------------------------------------------------------------------
__global__ __launch_bounds__(512, 1) void mfma3(
    const ushort_t* __restrict__ Ah, const ushort_t* __restrict__ Al,
    const ushort_t* __restrict__ Bh, const ushort_t* __restrict__ Bl,
    const float* __restrict__ bias, float* __restrict__ OUT,
    int nkt, int ldout)
{
    extern __shared__ __align__(16) ushort_t smem[];   // 2 * BUF2SZ ushorts

    const int tid  = threadIdx.x;
    const int wave = tid >> 6;
    const int lane = tid & 63;
    const int ntb = blockIdx.x, mtb = blockIdx.y;
    const int wr = wave >> 2;        // 0..1: 128-row slab
    const int wc = wave & 3;         // 0..3: 64-col slab

    f32x16 acc[4][2];
#pragma unroll
    for (int i = 0; i < 4; ++i)
#pragma unroll
        for (int j = 0; j < 2; ++j)
#pragma unroll
            for (int r = 0; r < 16; ++r) acc[i][j][r] = 0.f;

    const size_t a0 = (size_t)(2 * mtb) * nkt * 4096;
    const size_t a1 = a0 + (size_t)nkt * 4096;
    const size_t b0 = (size_t)(2 * ntb) * nkt * 4096;
    const size_t b1 = b0 + (size_t)nkt * 4096;

    // LDS per stage (ushort idx): Ah0 @0, Ah1 @4096, Al0 @8192, Al1 @12288,
    //                             Bh0 @16384, Bh1 @20480, Bl0 @24576, Bl1 @28672
#define STAGE2(slot, kt_) do {                                      \
        ushort_t* d = smem + (slot) * BUF2SZ;                       \
        const size_t ko = (size_t)(kt_) * 4096 + tid * 8;           \
        gload16(Ah + a0 + ko, d + tid * 8);                         \
        gload16(Ah + a1 + ko, d + 4096 + tid * 8);                  \
        gload16(Al + a0 + ko, d + 8192 + tid * 8);                  \
        gload16(Al + a1 + ko, d + 12288 + tid * 8);                 \
        gload16(Bh + b0 + ko, d + 16384 + tid * 8);                 \
        gload16(Bh + b1 + ko, d + 20480 + tid * 8);                 \
        gload16(Bl + b0 + ko, d + 24576 + tid * 8);                 \
        gload16(Bl + b1 + ko, d + 28672 + tid * 8);                 \
    } while (0)

    // per-lane fragment offsets (within a stage)
    const int lrow = lane & 31;          // row/col within 32-subtile
    const int kg   = lane >> 5;          // k-group (8 k values)
    const int aBase = wr * 4096;                                    // A tile = wr
    const int bBase = 16384 + (wc >> 1) * 4096;                     // B tile = wc>>1
    const int bCol  = (wc & 1) * 64;

    STAGE2(0, 0);

    for (int kt = 0; kt < nkt; ++kt) {
        asm volatile("s_waitcnt vmcnt(0)" ::: "memory");
        __builtin_amdgcn_sched_barrier(0);
        __builtin_amdgcn_s_barrier();          // stage(kt) visible; prev reads done
        if (kt + 1 < nkt) STAGE2((kt + 1) & 1, kt + 1);

        const ushort_t* p = smem + (kt & 1) * BUF2SZ;
#pragma unroll
        for (int kh = 0; kh < 2; ++kh) {
            const int ko = (kh * 2 + kg) * 1024;
            short8 a_h[4], a_l[4], b_h[2], b_l[2];
#pragma unroll
            for (int ms = 0; ms < 4; ++ms) {
                const int ao = aBase + ko + (ms * 32 + lrow) * 8;
                a_h[ms] = *(const short8*)&p[ao];
                a_l[ms] = *(const short8*)&p[8192 + ao];
            }
#pragma unroll
            for (int ns = 0; ns < 2; ++ns) {
                const int bo = bBase + ko + (bCol + ns * 32 + lrow) * 8;
                b_h[ns] = *(const short8*)&p[bo];
                b_l[ns] = *(const short8*)&p[8192 + bo];
            }
#pragma unroll
            for (int ms = 0; ms < 4; ++ms)
#pragma unroll
                for (int ns = 0; ns < 2; ++ns) {
                    acc[ms][ns] = __builtin_amdgcn_mfma_f32_32x32x16_bf16(a_h[ms], b_h[ns], acc[ms][ns], 0, 0, 0);
                    acc[ms][ns] = __builtin_amdgcn_mfma_f32_32x32x16_bf16(a_h[ms], b_l[ns], acc[ms][ns], 0, 0, 0);
                    acc[ms][ns] = __builtin_amdgcn_mfma_f32_32x32x16_bf16(a_l[ms], b_h[ns], acc[ms][ns], 0, 0, 0);
                }
        }
    }
#undef STAGE2

#pragma unroll
    for (int ms = 0; ms < 4; ++ms)
#pragma unroll
        for (int ns = 0; ns < 2; ++ns) {
            const int col = ntb * 256 + wc * 64 + ns * 32 + (lane & 31);
            const float bv = bias[col];
            const int rowb = mtb * 256 + wr * 128 + ms * 32 + 4 * (lane >> 5);
#pragma unroll
            for (int r = 0; r < 16; ++r) {
                const int row = rowb + (r & 3) + 8 * (r >> 2);
                OUT[(size_t)row * ldout + col] = acc[ms][ns][r] + bv;
            }
        }
}

// ---------------------------------------------------------------------------
// ps_splitk: partial[ks][m,n] = sum_{k in slice ks} h[m,k]*Wcomb[n,k]
// Wcomb = [Wst (2560 rows); Wout padded (256 rows)] -> N = 2816, 44 ntiles.
// 64x64 tile, K-split 4. All 4 K-iters staged at once (64 KB LDS), ONE
// barrier, then 48 straight MFMAs. 704 blocks -> TLP.
// ---------------------------------------------------------------------------
__global__ __launch_bounds__(256) void ps_splitk(
    const ushort_t* __restrict__ hH, const ushort_t* __restrict__ hL,
    const ushort_t* __restrict__ WcH, const ushort_t* __restrict__ WcL,
    float* __restrict__ partial)   // [4][256][2816]
{
    __shared__ ushort_t sAh[8192], sAl[8192], sBh[8192], sBl[8192]; // 64 KiB

    const int tid  = threadIdx.x;
    const int wave = tid >> 6;
    const int lane = tid & 63;
    const int ntile = blockIdx.x;   // 0..43
    const int mtile = blockIdx.y;   // 0..3
    const int ks    = blockIdx.z;   // 0..3
    const int amt = mtile >> 1, arh = mtile & 1;
    const int bmt = ntile >> 1, brh = ntile & 1;
    const int wr = wave >> 1, wc = wave & 1;

    f32x4 acc[2][2];
#pragma unroll
    for (int i = 0; i < 2; ++i)
#pragma unroll
        for (int j = 0; j < 2; ++j) acc[i][j] = (f32x4){0.f, 0.f, 0.f, 0.f};

    const int lw    = wave * 512;
    const int lsrcA = wave * 1024 + arh * 512 + lane * 8;
    const int lsrcB = wave * 1024 + brh * 512 + lane * 8;

#pragma unroll
    for (int ki = 0; ki < 4; ++ki) {
        const int kt = ks * 4 + ki;
        const size_t atile = ((size_t)(amt * NKT_H + kt)) * 4096;
        const size_t btile = ((size_t)(bmt * NKT_H + kt)) * 4096;
        gload16(hH  + atile + lsrcA, &sAh[ki * 2048 + lw]);
        gload16(hL  + atile + lsrcA, &sAl[ki * 2048 + lw]);
        gload16(WcH + btile + lsrcB, &sBh[ki * 2048 + lw]);
        gload16(WcL + btile + lsrcB, &sBl[ki * 2048 + lw]);
    }
    __syncthreads();   // single drain: all 16 stages visible

    const int kb = lane >> 4;
    const int lr = lane & 15;
#pragma unroll
    for (int ki = 0; ki < 4; ++ki) {
        short8 ah[2], al[2], bh[2], bl[2];
#pragma unroll
        for (int i = 0; i < 2; ++i) {
            const int ao = ki * 2048 + kb * 512 + (wr * 32 + i * 16 + lr) * 8;
            ah[i] = *(const short8*)&sAh[ao];
            al[i] = *(const short8*)&sAl[ao];
        }
#pragma unroll
        for (int j = 0; j < 2; ++j) {
            const int bo = ki * 2048 + kb * 512 + (wc * 32 + j * 16 + lr) * 8;
            bh[j] = *(const short8*)&sBh[bo];
            bl[j] = *(const short8*)&sBl[bo];
        }
#pragma unroll
        for (int i = 0; i < 2; ++i)
#pragma unroll
            for (int j = 0; j < 2; ++j) {
                acc[i][j] = __builtin_amdgcn_mfma_f32_16x16x32_bf16(ah[i], bh[j], acc[i][j], 0, 0, 0);
                acc[i][j] = __builtin_amdgcn_mfma_f32_16x16x32_bf16(ah[i], bl[j], acc[i][j], 0, 0, 0);
                acc[i][j] = __builtin_amdgcn_mfma_f32_16x16x32_bf16(al[i], bh[j], acc[i][j], 0, 0, 0);
            }
    }

    float* out = partial + ((size_t)ks * 256 + mtile * 64) * NCOMB + ntile * 64;
#pragma unroll
    for (int i = 0; i < 2; ++i) {
        const int row = wr * 32 + i * 16 + (lane >> 4) * 4;
#pragma unroll
        for (int j = 0; j < 2; ++j) {
            const int col = wc * 32 + j * 16 + (lane & 15);
#pragma unroll
            for (int r = 0; r < 4; ++r)
                out[(size_t)(row + r) * NCOMB + col] = acc[i][j][r];
        }
    }
}

// ---------------------------------------------------------------------------
// ew_gemm: EW[m,n] = sum_k embed[m,k] * Win[n, 4936+k]   (m<152, K=200)
// ---------------------------------------------------------------------------
__global__ __launch_bounds__(256) void ew_gemm(
    const float* __restrict__ embed, const float* __restrict__ Win,
    float* __restrict__ EW)
{
    __shared__ float As[16][68];
    __shared__ float Bs[16][68];
    const int tid = threadIdx.x;
    const int tx  = tid & 15;
    const int ty  = tid >> 4;
    const int n0  = blockIdx.x * 64;
    const int m0  = blockIdx.y * 64;
    const int lrow = tid >> 2;
    const int lk   = (tid & 3) * 4;

    float acc[4][4];
#pragma unroll
    for (int i = 0; i < 4; ++i)
#pragma unroll
        for (int j = 0; j < 4; ++j) acc[i][j] = 0.f;

    for (int k0 = 0; k0 < EMB; k0 += 16) {
        int k = k0 + lk;
        float4 av = {0.f,0.f,0.f,0.f}, bv = {0.f,0.f,0.f,0.f};
        if (k < EMB) {
            int am = m0 + lrow;
            if (am < 152) av = *(const float4*)(embed + (size_t)am * EMB + k);
            bv = *(const float4*)(Win + (size_t)(n0 + lrow) * DE + DIM + k);
        }
        __syncthreads();
        As[lk + 0][lrow] = av.x; As[lk + 1][lrow] = av.y;
        As[lk + 2][lrow] = av.z; As[lk + 3][lrow] = av.w;
        Bs[lk + 0][lrow] = bv.x; Bs[lk + 1][lrow] = bv.y;
        Bs[lk + 2][lrow] = bv.z; Bs[lk + 3][lrow] = bv.w;
        __syncthreads();
#pragma unroll
        for (int kk = 0; kk < 16; ++kk) {
            float4 a4 = *(const float4*)&As[kk][ty * 4];
            float4 b4 = *(const float4*)&Bs[kk][tx * 4];
            float avr[4] = {a4.x, a4.y, a4.z, a4.w};
            float bvr[4] = {b4.x, b4.y, b4.z, b4.w};
#pragma unroll
            for (int i = 0; i < 4; ++i)
#pragma unroll
                for (int j = 0; j < 4; ++j)
                    acc[i][j] = fmaf(avr[i], bvr[j], acc[i][j]);
        }
    }
#pragma unroll
    for (int i = 0; i < 4; ++i) {
        int m = m0 + ty * 4 + i;
        if (m < 152) {
#pragma unroll
            for (int j = 0; j < 4; ++j)
                EW[(size_t)m * SIXH + n0 + tx * 4 + j] = acc[i][j];
        }
    }
}

// ---------------------------------------------------------------------------
// pad_wout: padW[256][512] = Wout rows 0..150, zero rows 151..255
// ---------------------------------------------------------------------------
__global__ __launch_bounds__(256) void pad_wout(
    const float* __restrict__ Wout, float* __restrict__ padW)
{
    int i = blockIdx.x * 256 + threadIdx.x;
    if (i < 256 * 512) {
        int row = i >> 9;
        padW[i] = (row < NCLS) ? Wout[i] : 0.f;
    }
}

// init: c = 0, tiled h hi/lo = 0 (first ps partials == 0). In-graph -> det.
__global__ __launch_bounds__(256) void init_state(
    float* __restrict__ c, ushort_t* __restrict__ hHt, ushort_t* __restrict__ hLt)
{
    int i = blockIdx.x * 256 + threadIdx.x;
    if (i < BATCH * HID) { c[i] = 0.f; hHt[i] = 0; hLt[i] = 0; }
}

// ---------------------------------------------------------------------------
// step_fused(t): 256 blocks x 1 batch row.
//  1) preds[t-1] = b_out + sum_ks partial[ks][b][2560+cls]  (pred-deferral);
//     argmax -> commit[t-1] -> erow.
//  2) gates from px_t + EW[erow] + sum_ks partial cols 0..2559 + b_state;
//     c,h update; h emits (tiled bf16 for next ps, fp32 for finalize).
// ---------------------------------------------------------------------------
__global__ __launch_bounds__(256) void step_fused(
    const float* __restrict__ px_t,        // [256, 3072]
    const float* __restrict__ EW,          // [152, 3072]
    const float* __restrict__ partial,     // [4][256][2816]
    const float* __restrict__ b_state,     // [2560]
    const float* __restrict__ b_out,       // [151]
    int first,
    ushort_t* __restrict__ hHt, ushort_t* __restrict__ hLt,
    float* __restrict__ c, float* __restrict__ hF,
    float* __restrict__ dists_prev,        // dists[t-1] (unused if first)
    int*   __restrict__ commit_prev)       // commits[t-1] (write; unused if first)
{
    __shared__ float hs[HID];
    __shared__ float preds_s[NCLS + 1];
    __shared__ int   commit_sh;

    const int tid = threadIdx.x;
    const int b   = blockIdx.x;

    int erow = 0;
    if (!first) {
        if (tid < NCLS) {
            const float* pq = partial + (size_t)b * NCOMB + 2560;
            float pr = b_out[tid] + pq[tid]
                     + pq[(size_t)256 * NCOMB + tid]
                     + pq[(size_t)2 * 256 * NCOMB + tid]
                     + pq[(size_t)3 * 256 * NCOMB + tid];
            preds_s[tid] = pr;
            dists_prev[(size_t)b * NCLS + tid] = pr;
        }
        __syncthreads();
        if (tid == 0) {
            int bi = 1; float bv = preds_s[1];
            for (int n = 2; n < NCLS; ++n) {
                float v = preds_s[n];
                if (v > bv) { bv = v; bi = n; }
            }
            commit_prev[b] = bi;
            commit_sh = bi;
        }
        __syncthreads();
        erow = commit_sh + 1;
    }

    const float* ew = EW + (size_t)erow * SIXH;
    const float* px = px_t + (size_t)b * SIXH;
    const float* pp = partial + (size_t)b * NCOMB;

#pragma unroll
    for (int it = 0; it < 2; ++it) {
        const int u = it * 256 + tid;
        float p[6];
#pragma unroll
        for (int k2 = 0; k2 < 5; ++k2) {
            const int o = k2 * HID + u;
            float s = pp[o] + pp[(size_t)256 * NCOMB + o]
                    + pp[(size_t)2 * 256 * NCOMB + o] + pp[(size_t)3 * 256 * NCOMB + o];
            p[k2] = px[o] + ew[o] + s + b_state[o];
        }
        p[5] = px[5 * HID + u] + ew[5 * HID + u];

        float i_g = sigmoidf(p[0]);
        float f_g = sigmoidf(p[1]);
        float m_i = tanhf(p[2]);
        float o_g = sigmoidf(p[3]);
        float c_new = i_g * m_i + f_g * c[(size_t)b * HID + u];
        float outv  = o_g * tanhf(c_new);
        float hw    = sigmoidf(p[4]);
        float h_new = hw * outv + (1.f - hw) * p[5];
        c[(size_t)b * HID + u]  = c_new;
        hF[(size_t)b * HID + u] = h_new;
        hs[u] = h_new;
    }
    __syncthreads();

    // tiled bf16 h emit for next step's ps GEMM
    if (tid < 128) {
        const int half = tid >> 6;
        const int ch   = tid & 63;
        const int mt   = b >> 7;
        const int row  = b & 127;
        const size_t off = ((size_t)(mt * NKT_H + (ch >> 2))) * 4096
                         + (size_t)(ch & 3) * 1024 + (size_t)row * 8;
        alignas(16) ushort_t buf[8];
        if (half == 0) {
#pragma unroll
            for (int e = 0; e < 8; ++e) buf[e] = f2bf_rn(hs[ch * 8 + e]);
            *(uint4*)(hHt + off) = *(const uint4*)buf;
        } else {
#pragma unroll
            for (int e = 0; e < 8; ++e) {
                float x = hs[ch * 8 + e];
                buf[e] = f2bf_rn(x - bf2f(f2bf_rn(x)));
            }
            *(uint4*)(hLt + off) = *(const uint4*)buf;
        }
    }
}

// ---------------------------------------------------------------------------
// finalize_last: preds for t = T-1 from fp32 h, argmax, dists+commits write.
// ---------------------------------------------------------------------------
__global__ __launch_bounds__(192) void finalize_last(
    const float* __restrict__ hF, const float* __restrict__ Wout,
    const float* __restrict__ b_out,
    float* __restrict__ dists_last, int* __restrict__ commits_last)
{
    __shared__ float hsh[HID];
    __shared__ float preds[NCLS + 1];
    const int b = blockIdx.x;
    const int tid = threadIdx.x;

    if (tid < 128) {
        float4 v = *(const float4*)(hF + (size_t)b * HID + tid * 4);
        *(float4*)&hsh[tid * 4] = v;
    }
    __syncthreads();
    if (tid < NCLS) {
        const float* w = Wout + (size_t)tid * HID;
        float s0 = 0.f, s1 = 0.f, s2 = 0.f, s3 = 0.f;
        for (int k = 0; k < HID; k += 4) {
            float4 w4 = *(const float4*)(w + k);
            float4 h4 = *(const float4*)&hsh[k];
            s0 = fmaf(h4.x, w4.x, s0);
            s1 = fmaf(h4.y, w4.y, s1);
            s2 = fmaf(h4.z, w4.z, s2);
            s3 = fmaf(h4.w, w4.w, s3);
        }
        float s = b_out[tid] + ((s0 + s1) + (s2 + s3));
        preds[tid] = s;
        dists_last[(size_t)b * NCLS + tid] = s;
    }
    __syncthreads();
    if (tid == 0) {
        int bi = 1; float bv = preds[1];
        for (int n = 2; n < NCLS; ++n) {
            float v = preds[n];
            if (v > bv) { bv = v; bi = n; }
        }
        commits_last[b] = bi;
    }
}

// ---------------------------------------------------------------------------
__global__ __launch_bounds__(192) void gather_out(
    const float* __restrict__ dists, const int* __restrict__ commits,
    const int* __restrict__ gidx, float* __restrict__ out)
{
    const int i = blockIdx.x;
    const int g = gidx[i];
    if (threadIdx.x < NCLS)
        out[(size_t)i * NCLS + threadIdx.x] = dists[(size_t)g * NCLS + threadIdx.x];
    if (threadIdx.x == NCLS)
        out[(size_t)NPACK * NCLS + i] = (float)commits[g];
}

// ---------------------------------------------------------------------------
extern "C" void kernel_launch(void* const* d_in, const int* in_sizes, int n_in,
                              void* d_out, int out_size, void* d_ws, size_t ws_size,
                              hipStream_t stream)
{
    const float* X      = (const float*)d_in[0];  // [80,256,4936]
    const float* embed  = (const float*)d_in[1];  // [152,200]
    const float* Win    = (const float*)d_in[2];  // [3072,5136]
    const float* b_in   = (const float*)d_in[3];
    const float* Wst    = (const float*)d_in[4];  // [2560,512]
    const float* b_st   = (const float*)d_in[5];
    const float* Wout   = (const float*)d_in[6];  // [151,512]
    const float* b_out  = (const float*)d_in[7];
    const int*   gidx   = (const int*)d_in[8];

    // raise dynamic-LDS cap for mfma3 (idempotent; capture-safe host call)
    hipFuncSetAttribute((const void*)mfma3,
                        hipFuncAttributeMaxDynamicSharedMemorySize,
                        2 * BUF2SZ * 2);

    const size_t WN  = (size_t)24 * NKT * 4096;     // ushorts per Win-split array
    const size_t WCN = (size_t)22 * NKT_H * 4096;   // ushorts per Wcomb-split array
    const size_t HN  = (size_t)2 * NKT_H * 4096;    // ushorts per h-split array

    ushort_t* Wh  = (ushort_t*)d_ws;
    ushort_t* Wl  = Wh + WN;
    ushort_t* WcH = Wl + WN;
    ushort_t* WcL = WcH + WCN;
    ushort_t* hHt = WcL + WCN;
    ushort_t* hLt = hHt + HN;
    float* EW      = (float*)(hLt + HN);
    float* partial = EW + (size_t)152 * SIXH;             // 4*256*2816
    float* c       = partial + (size_t)4 * BATCH * NCOMB;
    float* hF      = c + (size_t)BATCH * HID;
    float* padW    = hF + (size_t)BATCH * HID;            // 256*512
    float* dists   = padW + (size_t)256 * HID;
    int* commits   = (int*)(dists + (size_t)T_STEPS * BATCH * NCLS);
    char* cbase    = (char*)(commits + T_STEPS * BATCH);

    size_t off = (size_t)(cbase - (char*)d_ws);
    off = (off + 255) & ~(size_t)255;
    const size_t per_t = (size_t)2 * 2 * NKT * 4096 * 2 + (size_t)BATCH * SIXH * 4;
    size_t rem = (ws_size > off) ? (ws_size - off) : 0;
    int CT = (int)(rem / per_t);
    if (CT > T_STEPS) CT = T_STEPS;
    if (CT < 1) CT = 1;

    ushort_t* Xh = (ushort_t*)((char*)d_ws + off);
    ushort_t* Xl = Xh + (size_t)2 * CT * NKT * 4096;
    float* px    = (float*)(Xl + (size_t)2 * CT * NKT * 4096);

    // one-time prep
    convert_split<<<dim3(NKT, 24), 256, 0, stream>>>(Win, DE, DIM, Wh, Wl, NKT);
    convert_split<<<dim3(NKT_H, 20), 256, 0, stream>>>(Wst, HID, HID, WcH, WcL, NKT_H);
    pad_wout<<<512, 256, 0, stream>>>(Wout, padW);
    convert_split<<<dim3(NKT_H, 2), 256, 0, stream>>>(
        padW, HID, HID, WcH + (size_t)20 * NKT_H * 4096, WcL + (size_t)20 * NKT_H * 4096, NKT_H);
    ew_gemm<<<dim3(SIXH / 64, 3), 256, 0, stream>>>(embed, Win, EW);
    init_state<<<512, 256, 0, stream>>>(c, hHt, hLt);

    for (int t0 = 0; t0 < T_STEPS; t0 += CT) {
        int nt = T_STEPS - t0;
        if (nt > CT) nt = CT;
        convert_split<<<dim3(NKT, 2 * nt), 256, 0, stream>>>(
            X + (size_t)t0 * BATCH * DIM, DIM, DIM, Xh, Xl, NKT);
        mfma3<<<dim3(SIXH / 256, nt), 512, 2 * BUF2SZ * 2, stream>>>(
            Xh, Xl, Wh, Wl, b_in, px, NKT, SIXH);
        for (int t = t0; t < t0 + nt; ++t) {
            const int tp = (t > 0) ? t - 1 : 0;
            ps_splitk<<<dim3(44, 4, 4), 256, 0, stream>>>(
                hHt, hLt, WcH, WcL, partial);
            step_fused<<<BATCH, 256, 0, stream>>>(
                px + (size_t)(t - t0) * BATCH * SIXH, EW, partial, b_st, b_out,
                (t == 0) ? 1 : 0, hHt, hLt, c, hF,
                dists + (size_t)tp * BATCH * NCLS, commits + (size_t)tp * BATCH);
        }
    }

    finalize_last<<<BATCH, 192, 0, stream>>>(
        hF, Wout, b_out,
        dists + (size_t)(T_STEPS - 1) * BATCH * NCLS,
        commits + (size_t)(T_STEPS - 1) * BATCH);

    gather_out<<<NPACK, 192, 0, stream>>>(dists, commits, gidx, (float*)d_out);
}